// Round 2
// baseline (46452.502 us; speedup 1.0000x reference)
//
#include <hip/hip_runtime.h>
#include <cstdint>

typedef uint32_t u32;
typedef _Float16 half2_t __attribute__((ext_vector_type(2)));

static __device__ __forceinline__ u32 pack2(float a, float b) {
    half2_t v;
    v.x = (_Float16)a;
    v.y = (_Float16)b;
    return __builtin_bit_cast(u32, v);
}

static __device__ __forceinline__ float dot2(u32 a, u32 b, float c) {
    return __builtin_amdgcn_fdot2(__builtin_bit_cast(half2_t, a),
                                  __builtin_bit_cast(half2_t, b), c, false);
}

static __device__ __forceinline__ unsigned short f16bits(float v) {
    return __builtin_bit_cast(unsigned short, (_Float16)v);
}

// barrier without vmcnt(0) drain (global enc stores must not stall the loop)
#define BAR() asm volatile("s_waitcnt lgkmcnt(0)\n\ts_barrier" ::: "memory")

// ---------------------------------------------------------------------------
// RNN kernel: 1 workgroup, 512 threads (8 waves), persistent over T steps.
// Waves 0-3 (IH): critical chain  y(s,l) = relu(Wih_l . cur + pre[l]).
// Waves 4-7 (HH): shadow chain    pre[lp] = Whh_lp . y + b_lp  (1+ slot slack).
// Both groups read the SAME vector ybuf[(l+3)&3] in slot l.
// Lane layout (both groups): row = (wave&3)*32 + (lane>>1), col-half c=lane&1.
// Per lane per slot: 8 ds_read_b128 (2-addr broadcast) + 32 v_dot2_f32_f16.
// Weights resident in VGPRs as f16 pairs (128 VGPRs). State f16 in LDS.
// ---------------------------------------------------------------------------
__global__ __launch_bounds__(512) void rnn_kernel(
    const float* __restrict__ x0,
    const float* __restrict__ Wih, const float* __restrict__ Whh,
    const float* __restrict__ bih, const float* __restrict__ bhh,
    float* __restrict__ enc, int T)
{
    __shared__ u32 ybuf[4][64];     // per-layer output, f16 pairs
    __shared__ float pre[4][128];   // Whh.h + biases, f32

    const int tid  = threadIdx.x;
    const int wave = tid >> 6;
    const int lane = tid & 63;
    const bool isIH = wave < 4;
    const int gw   = wave & 3;
    const int row  = gw * 32 + (lane >> 1);
    const int c    = lane & 1;

    // ---- preload weights: IH waves hold Wih rows, HH waves hold Whh rows
    u32 wreg[4][32];
    {
        const float* WB = isIH ? Wih : Whh;
        #pragma unroll
        for (int l = 0; l < 4; ++l) {
            const float* p = WB + (size_t)(l * 128 + row) * 128 + c * 64;
            #pragma unroll
            for (int m = 0; m < 32; ++m)
                wreg[l][m] = pack2(p[2 * m], p[2 * m + 1]);
        }
    }
    float bsum[4];
    #pragma unroll
    for (int l = 0; l < 4; ++l)
        bsum[l] = bih[l * 128 + row] + bhh[l * 128 + row];

    // ---- LDS init: ybuf[0]=f16(x), ybuf[1..3]=0
    if (tid < 64)       ybuf[0][tid] = pack2(x0[2 * tid], x0[2 * tid + 1]);
    else if (tid < 256) ((u32*)ybuf)[tid] = 0u;
    BAR();

#define DOT(WL, SRC, SEED, OUT) do {                                        \
        const u32* vb = &(SRC)[c * 32];                                     \
        uint4 q0 = *(const uint4*)(vb + 0);                                 \
        uint4 q1 = *(const uint4*)(vb + 4);                                 \
        uint4 q2 = *(const uint4*)(vb + 8);                                 \
        uint4 q3 = *(const uint4*)(vb + 12);                                \
        uint4 q4 = *(const uint4*)(vb + 16);                                \
        uint4 q5 = *(const uint4*)(vb + 20);                                \
        uint4 q6 = *(const uint4*)(vb + 24);                                \
        uint4 q7 = *(const uint4*)(vb + 28);                                \
        float a0 = (SEED), a1 = 0.f, a2 = 0.f, a3 = 0.f;                    \
        a0 = dot2(q0.x, (WL)[0], a0);  a1 = dot2(q0.y, (WL)[1], a1);        \
        a2 = dot2(q0.z, (WL)[2], a2);  a3 = dot2(q0.w, (WL)[3], a3);        \
        a0 = dot2(q1.x, (WL)[4], a0);  a1 = dot2(q1.y, (WL)[5], a1);        \
        a2 = dot2(q1.z, (WL)[6], a2);  a3 = dot2(q1.w, (WL)[7], a3);        \
        a0 = dot2(q2.x, (WL)[8], a0);  a1 = dot2(q2.y, (WL)[9], a1);        \
        a2 = dot2(q2.z, (WL)[10], a2); a3 = dot2(q2.w, (WL)[11], a3);       \
        a0 = dot2(q3.x, (WL)[12], a0); a1 = dot2(q3.y, (WL)[13], a1);       \
        a2 = dot2(q3.z, (WL)[14], a2); a3 = dot2(q3.w, (WL)[15], a3);       \
        a0 = dot2(q4.x, (WL)[16], a0); a1 = dot2(q4.y, (WL)[17], a1);       \
        a2 = dot2(q4.z, (WL)[18], a2); a3 = dot2(q4.w, (WL)[19], a3);       \
        a0 = dot2(q5.x, (WL)[20], a0); a1 = dot2(q5.y, (WL)[21], a1);       \
        a2 = dot2(q5.z, (WL)[22], a2); a3 = dot2(q5.w, (WL)[23], a3);       \
        a0 = dot2(q6.x, (WL)[24], a0); a1 = dot2(q6.y, (WL)[25], a1);       \
        a2 = dot2(q6.z, (WL)[26], a2); a3 = dot2(q6.w, (WL)[27], a3);       \
        a0 = dot2(q7.x, (WL)[28], a0); a1 = dot2(q7.y, (WL)[29], a1);       \
        a2 = dot2(q7.z, (WL)[30], a2); a3 = dot2(q7.w, (WL)[31], a3);       \
        OUT = (a0 + a1) + (a2 + a3);                                        \
    } while (0)

    // ---- init pre[]: layer0 hid = x -> pre[0]=Whh0.x+b0; layers 1,2 -> bias
    // (pre[3] is produced in slot 0 of step 0 from ybuf[3]=0 -> = b3)
    if (!isIH) {
        float v;
        DOT(wreg[0], ybuf[0], (c == 0) ? bsum[0] : 0.f, v);
        v += __shfl_xor(v, 1);
        if (c == 0) {
            pre[0][row] = v;
            pre[1][row] = bsum[1];
            pre[2][row] = bsum[2];
            pre[3][row] = bsum[3];
        }
    }
    BAR();

    // ---- main loop: 4 slots/step, 1 barrier/slot
    for (int s = 0; s < T; ++s) {
        #pragma unroll
        for (int l = 0; l < 4; ++l) {
            const int lp = (l + 3) & 3;   // source buffer / HH layer index
            if (isIH) {
                float p = pre[l][row];    // issued early, latency hidden
                float v;
                DOT(wreg[l], ybuf[lp], 0.f, v);
                v += __shfl_xor(v, 1);
                float y = fmaxf(v + p, 0.f);
                float yo = __shfl_xor(y, 2);
                if ((lane & 3) == 0)
                    ybuf[l][gw * 16 + (lane >> 2)] = pack2(y, yo);
                if (l == 3 && c == 0)
                    enc[(size_t)s * 128 + row] = y;
            } else {
                float v;
                DOT(wreg[lp], ybuf[lp], (c == 0) ? bsum[lp] : 0.f, v);
                v += __shfl_xor(v, 1);
                if (c == 0)
                    pre[lp][row] = v;
            }
            BAR();
        }
    }
#undef DOT
}

// ---------------------------------------------------------------------------
// Heads kernel: grid (3 heads, T/32 row-segments), 256 threads. (unchanged)
// ---------------------------------------------------------------------------
__global__ __launch_bounds__(256) void heads_kernel(
    const float* __restrict__ enc,
    const float* __restrict__ arw, const float* __restrict__ arb,
    const float* __restrict__ aw,  const float* __restrict__ ab,
    const float* __restrict__ prw, const float* __restrict__ prb,
    const float* __restrict__ pw,  const float* __restrict__ pb,
    const float* __restrict__ mrw, const float* __restrict__ mrb,
    const float* __restrict__ mw,  const float* __restrict__ mb,
    float* __restrict__ out, int T)
{
    const int head = blockIdx.x;
    const int r0 = blockIdx.y * 32;
    if (r0 >= T) return;

    const float *rbw, *rbb, *ow, *ob;
    int od, oc;
    if (head == 0)      { rbw = arw; rbb = arb; ow = aw; ob = ab; od = 8; oc = 0; }
    else if (head == 1) { rbw = prw; rbb = prb; ow = pw; ob = pb; od = 1; oc = 8; }
    else                { rbw = mrw; rbb = mrb; ow = mw; ob = mb; od = 1; oc = 9; }

    __shared__ u32 xs[32][64];
    __shared__ u32 hs[32][64];

    const int tid = threadIdx.x;

    #pragma unroll
    for (int rep = 0; rep < 8; ++rep) {
        int u = tid + rep * 256;
        int row = u >> 6, p = u & 63;
        const float* e = enc + (size_t)(r0 + row) * 128 + 2 * p;
        xs[row][p] = pack2(e[0], e[1]);
    }
    __syncthreads();

    const int j = tid & 127;
    const int rh = tid >> 7;

    float acc[16];
    u32 wreg[64];

#define PACKW(WPTR) do {                                                    \
        const float* _w = (WPTR);                                           \
        _Pragma("unroll")                                                   \
        for (int cc = 0; cc < 16; ++cc) {                                   \
            float4 aa = *(const float4*)(_w + cc * 8);                      \
            float4 bb = *(const float4*)(_w + cc * 8 + 4);                  \
            wreg[cc * 4 + 0] = pack2(aa.x, aa.y);                           \
            wreg[cc * 4 + 1] = pack2(aa.z, aa.w);                           \
            wreg[cc * 4 + 2] = pack2(bb.x, bb.y);                           \
            wreg[cc * 4 + 3] = pack2(bb.z, bb.w);                           \
        }                                                                   \
    } while (0)

#define MM16(SRC) do {                                                      \
        _Pragma("unroll")                                                   \
        for (int r = 0; r < 16; ++r) acc[r] = 0.f;                          \
        _Pragma("unroll")                                                   \
        for (int kp = 0; kp < 16; ++kp) {                                   \
            u32 w0 = wreg[kp * 4 + 0], w1 = wreg[kp * 4 + 1];               \
            u32 w2 = wreg[kp * 4 + 2], w3 = wreg[kp * 4 + 3];               \
            _Pragma("unroll")                                               \
            for (int r = 0; r < 16; ++r) {                                  \
                uint4 x4 = *(const uint4*)(&SRC[rh * 16 + r][kp * 4]);      \
                acc[r] = dot2(x4.x, w0, acc[r]);                            \
                acc[r] = dot2(x4.y, w1, acc[r]);                            \
                acc[r] = dot2(x4.z, w2, acc[r]);                            \
                acc[r] = dot2(x4.w, w3, acc[r]);                            \
            }                                                               \
        }                                                                   \
    } while (0)

    #pragma unroll
    for (int blk = 0; blk < 2; ++blk) {
        PACKW(rbw + (size_t)((blk * 2 + 0) * 128 + j) * 128);
        MM16(xs);
        {
            float b1 = rbb[(blk * 2 + 0) * 128 + j];
            #pragma unroll
            for (int r = 0; r < 16; ++r) {
                float v = acc[r] + b1;
                v = fmaxf(v, 0.2f * v);
                reinterpret_cast<unsigned short*>(&hs[rh * 16 + r][0])[j] = f16bits(v);
            }
        }
        __syncthreads();

        PACKW(rbw + (size_t)((blk * 2 + 1) * 128 + j) * 128);
        MM16(hs);
        {
            float b2 = rbb[(blk * 2 + 1) * 128 + j];
            #pragma unroll
            for (int r = 0; r < 16; ++r) {
                int row = rh * 16 + r;
                unsigned short xb =
                    reinterpret_cast<const unsigned short*>(&xs[row][0])[j];
                float xold = (float)__builtin_bit_cast(_Float16, xb);
                float v = xold + acc[r] + b2;
                v = fmaxf(v, 0.2f * v);
                reinterpret_cast<unsigned short*>(&xs[row][0])[j] = f16bits(v);
            }
        }
        __syncthreads();
    }

    {
        const int o = tid & 15;
        const int rr = tid >> 4;
        if (o < od) {
            PACKW(ow + (size_t)o * 128);
            float obv = ob[o];
            #pragma unroll
            for (int rs = 0; rs < 2; ++rs) {
                const int row = rr * 2 + rs;
                float a = 0.f;
                #pragma unroll
                for (int kp = 0; kp < 64; ++kp) a = dot2(xs[row][kp], wreg[kp], a);
                out[(size_t)(r0 + row) * 10 + oc + o] = a + obv;
            }
        }
    }
#undef PACKW
#undef MM16
}

extern "C" void kernel_launch(void* const* d_in, const int* in_sizes, int n_in,
                              void* d_out, int out_size, void* d_ws, size_t ws_size,
                              hipStream_t stream)
{
    const float* x   = (const float*)d_in[0];
    const float* Wih = (const float*)d_in[1];
    const float* Whh = (const float*)d_in[2];
    const float* bih = (const float*)d_in[3];
    const float* bhh = (const float*)d_in[4];
    const float* arw = (const float*)d_in[5];
    const float* arb = (const float*)d_in[6];
    const float* aw  = (const float*)d_in[7];
    const float* ab  = (const float*)d_in[8];
    const float* prw = (const float*)d_in[9];
    const float* prb = (const float*)d_in[10];
    const float* pw  = (const float*)d_in[11];
    const float* pb  = (const float*)d_in[12];
    const float* mrw = (const float*)d_in[13];
    const float* mrb = (const float*)d_in[14];
    const float* mw  = (const float*)d_in[15];
    const float* mb  = (const float*)d_in[16];

    const int T = out_size / 10;             // 32768
    float* enc = (float*)d_ws;               // T*128 fp32 = 16 MB scratch

    rnn_kernel<<<1, 512, 0, stream>>>(x, Wih, Whh, bih, bhh, enc, T);

    heads_kernel<<<dim3(3, (T + 31) / 32), 256, 0, stream>>>(
        enc, arw, arb, aw, ab, prw, prb, pw, pb, mrw, mrb, mw, mb,
        (float*)d_out, T);
}

// Round 3
// 39848.578 us; speedup vs baseline: 1.1657x; 1.1657x over previous
//
#include <hip/hip_runtime.h>
#include <cstdint>

typedef uint32_t u32;
typedef _Float16 f16;
typedef f16 f16x2 __attribute__((ext_vector_type(2)));
typedef f16 f16x8 __attribute__((ext_vector_type(8)));
typedef float f32x4 __attribute__((ext_vector_type(4)));

static __device__ __forceinline__ u32 pack2(float a, float b) {
    f16x2 v;
    v.x = (f16)a;
    v.y = (f16)b;
    return __builtin_bit_cast(u32, v);
}

static __device__ __forceinline__ float dot2(u32 a, u32 b, float c) {
    return __builtin_amdgcn_fdot2(__builtin_bit_cast(f16x2, a),
                                  __builtin_bit_cast(f16x2, b), c, false);
}

static __device__ __forceinline__ unsigned short f16bits(float v) {
    return __builtin_bit_cast(unsigned short, (f16)v);
}

// barrier without vmcnt(0) drain (global enc stores must not stall the loop)
#define BAR() asm volatile("s_waitcnt lgkmcnt(0)\n\ts_barrier" ::: "memory")

#define MFMA(A, B, C) __builtin_amdgcn_mfma_f32_16x16x32_f16(A, B, C, 0, 0, 0)

// ---------------------------------------------------------------------------
// RNN kernel: 1 workgroup, 256 threads (4 waves), persistent over T steps.
// Per slot (layer l): y = relu([Wih_l | Whh_l] . [cur; hid_l] + b)  (K=256)
// via v_mfma_f32_16x16x32_f16. Wave w owns rows 32w..32w+31 (2 M-tiles).
// A-frags (weights) resident: 4 layers x 2 tiles x 8 k-tiles = 256 VGPRs.
// B built with ALL 16 columns = x  ->  every lane's D holds 4 valid rows,
// no shuffle reduce; lane m==0 of each 16-group writes 2 packed u32.
// HH B-frags (hid part, stable >=3 slots) are prefetched one slot early
// into ping-pong regs so the 8 HH MFMAs overlap the IH LDS-read latency.
// State f16 in LDS ping-pong buf[2][4][64]; 1 barrier/slot (lgkmcnt only).
// ---------------------------------------------------------------------------
__global__ __launch_bounds__(256, 1) void rnn_kernel(
    const float* __restrict__ x0,
    const float* __restrict__ Wih, const float* __restrict__ Whh,
    const float* __restrict__ bih, const float* __restrict__ bhh,
    u32* __restrict__ enc, int T)
{
    __shared__ u32 buf[2][4][64];

    const int tid  = threadIdx.x;
    const int w    = tid >> 6;     // wave 0..3
    const int lane = tid & 63;
    const int m    = lane & 15;    // row-in-tile (A) / col n (B,D)
    const int g    = lane >> 4;    // k-group 0..3

    // ---- resident A fragments + bias
    f16x8 a[4][2][8];              // [layer][tile][ktile]
    f32x4 bias[4][2];
    #pragma unroll
    for (int l = 0; l < 4; ++l) {
        #pragma unroll
        for (int t = 0; t < 2; ++t) {
            const int row = w * 32 + t * 16 + m;
            #pragma unroll
            for (int kt = 0; kt < 8; ++kt) {
                const float* W = (kt < 4) ? Wih : Whh;
                const float* p = W + ((size_t)(l * 128 + row)) * 128
                                   + (kt & 3) * 32 + g * 8;
                f16x8 v;
                #pragma unroll
                for (int e = 0; e < 8; ++e) v[e] = (f16)p[e];
                a[l][t][kt] = v;
            }
            const int r4 = w * 32 + t * 16 + g * 4;
            f32x4 b;
            #pragma unroll
            for (int r = 0; r < 4; ++r)
                b[r] = bih[l * 128 + r4 + r] + bhh[l * 128 + r4 + r];
            bias[l][t] = b;
        }
    }

    // ---- LDS init: buf[1] = { f16(x), 0, 0, 0 }   (step 0 reads parity 1)
    if (tid < 64)       buf[1][0][tid] = pack2(x0[2 * tid], x0[2 * tid + 1]);
    else if (tid < 256) ((u32*)buf[1])[tid] = 0u;
    __syncthreads();

    // ---- initial HH prefetch for slot 0 of step 0: hid_0 = buf[1][0]
    f16x8 hpA[4], hpB[4];
    {
        const u32* h0 = &buf[1][0][0];
        #pragma unroll
        for (int j = 0; j < 4; ++j)
            hpA[j] = *(const f16x8*)(h0 + j * 16 + g * 4);
    }

    // One layer-slot. HIN = prefetched hid frags (ready), HOUT = prefetch
    // target for the NEXT slot's hid. CURB = this slot's cur vector (written
    // last slot), NXTB = next slot's hid source (stable, >=1 step old).
#define SLOT(l, HIN, HOUT, CURB, NXTB, STORE_ENC) do {                        \
        const u32* _cb = (CURB);                                              \
        const u32* _nb = (NXTB);                                              \
        f16x8 i0 = *(const f16x8*)(_cb + 0 * 16 + g * 4);                     \
        f16x8 i1 = *(const f16x8*)(_cb + 1 * 16 + g * 4);                     \
        f16x8 i2 = *(const f16x8*)(_cb + 2 * 16 + g * 4);                     \
        f16x8 i3 = *(const f16x8*)(_cb + 3 * 16 + g * 4);                     \
        HOUT[0] = *(const f16x8*)(_nb + 0 * 16 + g * 4);                      \
        HOUT[1] = *(const f16x8*)(_nb + 1 * 16 + g * 4);                      \
        HOUT[2] = *(const f16x8*)(_nb + 2 * 16 + g * 4);                      \
        HOUT[3] = *(const f16x8*)(_nb + 3 * 16 + g * 4);                      \
        u32* _wb = &buf[_p][l][0];                                            \
        _Pragma("unroll")                                                     \
        for (int t = 0; t < 2; ++t) {                                         \
            f32x4 c0 = bias[l][t];                                            \
            f32x4 c1 = {0.f, 0.f, 0.f, 0.f};                                  \
            c0 = MFMA(a[l][t][4], HIN[0], c0);   /* HH: data ready */         \
            c1 = MFMA(a[l][t][5], HIN[1], c1);                                \
            c0 = MFMA(a[l][t][6], HIN[2], c0);                                \
            c1 = MFMA(a[l][t][7], HIN[3], c1);                                \
            c0 = MFMA(a[l][t][0], i0, c0);       /* IH: waits on LDS */       \
            c1 = MFMA(a[l][t][1], i1, c1);                                    \
            c0 = MFMA(a[l][t][2], i2, c0);                                    \
            c1 = MFMA(a[l][t][3], i3, c1);                                    \
            f32x4 d = c0 + c1;                                                \
            float y0 = fmaxf(d[0], 0.f), y1 = fmaxf(d[1], 0.f);               \
            float y2 = fmaxf(d[2], 0.f), y3 = fmaxf(d[3], 0.f);               \
            u32 w0 = pack2(y0, y1), w1 = pack2(y2, y3);                       \
            if (m == 0) {                                                     \
                *(uint2*)(_wb + w * 16 + t * 8 + g * 2) = make_uint2(w0, w1); \
                if (STORE_ENC)                                                \
                    *(uint2*)(enc + (size_t)s * 64 + w * 16 + t * 8 + g * 2)  \
                        = make_uint2(w0, w1);                                 \
            }                                                                 \
        }                                                                     \
        BAR();                                                                \
    } while (0)

    for (int s = 0; s < T; ++s) {
        const int _p = s & 1;
        const int _q = _p ^ 1;
        SLOT(0, hpA, hpB, &buf[_q][3][0], &buf[_q][1][0], 0);
        SLOT(1, hpB, hpA, &buf[_p][0][0], &buf[_q][2][0], 0);
        SLOT(2, hpA, hpB, &buf[_p][1][0], &buf[_q][3][0], 0);
        SLOT(3, hpB, hpA, &buf[_p][2][0], &buf[_p][0][0], 1);
    }
#undef SLOT
}

// ---------------------------------------------------------------------------
// Heads kernel: grid (3 heads, T/32 row-segments), 256 threads.
// enc is now f16-pairs (u32) -> staging is a direct copy.
// ---------------------------------------------------------------------------
__global__ __launch_bounds__(256) void heads_kernel(
    const u32* __restrict__ enc,
    const float* __restrict__ arw, const float* __restrict__ arb,
    const float* __restrict__ aw,  const float* __restrict__ ab,
    const float* __restrict__ prw, const float* __restrict__ prb,
    const float* __restrict__ pw,  const float* __restrict__ pb,
    const float* __restrict__ mrw, const float* __restrict__ mrb,
    const float* __restrict__ mw,  const float* __restrict__ mb,
    float* __restrict__ out, int T)
{
    const int head = blockIdx.x;
    const int r0 = blockIdx.y * 32;
    if (r0 >= T) return;

    const float *rbw, *rbb, *ow, *ob;
    int od, oc;
    if (head == 0)      { rbw = arw; rbb = arb; ow = aw; ob = ab; od = 8; oc = 0; }
    else if (head == 1) { rbw = prw; rbb = prb; ow = pw; ob = pb; od = 1; oc = 8; }
    else                { rbw = mrw; rbb = mrb; ow = mw; ob = mb; od = 1; oc = 9; }

    __shared__ u32 xs[32][64];
    __shared__ u32 hs[32][64];

    const int tid = threadIdx.x;

    #pragma unroll
    for (int rep = 0; rep < 8; ++rep) {
        int u = tid + rep * 256;
        int row = u >> 6, p = u & 63;
        xs[row][p] = enc[(size_t)(r0 + row) * 64 + p];
    }
    __syncthreads();

    const int j = tid & 127;
    const int rh = tid >> 7;

    float acc[16];
    u32 wreg[64];

#define PACKW(WPTR) do {                                                    \
        const float* _w = (WPTR);                                           \
        _Pragma("unroll")                                                   \
        for (int cc = 0; cc < 16; ++cc) {                                   \
            float4 aa = *(const float4*)(_w + cc * 8);                      \
            float4 bb = *(const float4*)(_w + cc * 8 + 4);                  \
            wreg[cc * 4 + 0] = pack2(aa.x, aa.y);                           \
            wreg[cc * 4 + 1] = pack2(aa.z, aa.w);                           \
            wreg[cc * 4 + 2] = pack2(bb.x, bb.y);                           \
            wreg[cc * 4 + 3] = pack2(bb.z, bb.w);                           \
        }                                                                   \
    } while (0)

#define MM16(SRC) do {                                                      \
        _Pragma("unroll")                                                   \
        for (int r = 0; r < 16; ++r) acc[r] = 0.f;                          \
        _Pragma("unroll")                                                   \
        for (int kp = 0; kp < 16; ++kp) {                                   \
            u32 w0 = wreg[kp * 4 + 0], w1 = wreg[kp * 4 + 1];               \
            u32 w2 = wreg[kp * 4 + 2], w3 = wreg[kp * 4 + 3];               \
            _Pragma("unroll")                                               \
            for (int r = 0; r < 16; ++r) {                                  \
                uint4 x4 = *(const uint4*)(&SRC[rh * 16 + r][kp * 4]);      \
                acc[r] = dot2(x4.x, w0, acc[r]);                            \
                acc[r] = dot2(x4.y, w1, acc[r]);                            \
                acc[r] = dot2(x4.z, w2, acc[r]);                            \
                acc[r] = dot2(x4.w, w3, acc[r]);                            \
            }                                                               \
        }                                                                   \
    } while (0)

    #pragma unroll
    for (int blk = 0; blk < 2; ++blk) {
        PACKW(rbw + (size_t)((blk * 2 + 0) * 128 + j) * 128);
        MM16(xs);
        {
            float b1 = rbb[(blk * 2 + 0) * 128 + j];
            #pragma unroll
            for (int r = 0; r < 16; ++r) {
                float v = acc[r] + b1;
                v = fmaxf(v, 0.2f * v);
                reinterpret_cast<unsigned short*>(&hs[rh * 16 + r][0])[j] = f16bits(v);
            }
        }
        __syncthreads();

        PACKW(rbw + (size_t)((blk * 2 + 1) * 128 + j) * 128);
        MM16(hs);
        {
            float b2 = rbb[(blk * 2 + 1) * 128 + j];
            #pragma unroll
            for (int r = 0; r < 16; ++r) {
                int row = rh * 16 + r;
                unsigned short xb =
                    reinterpret_cast<const unsigned short*>(&xs[row][0])[j];
                float xold = (float)__builtin_bit_cast(f16, xb);
                float v = xold + acc[r] + b2;
                v = fmaxf(v, 0.2f * v);
                reinterpret_cast<unsigned short*>(&xs[row][0])[j] = f16bits(v);
            }
        }
        __syncthreads();
    }

    {
        const int o = tid & 15;
        const int rr = tid >> 4;
        if (o < od) {
            PACKW(ow + (size_t)o * 128);
            float obv = ob[o];
            #pragma unroll
            for (int rs = 0; rs < 2; ++rs) {
                const int row = rr * 2 + rs;
                float a = 0.f;
                #pragma unroll
                for (int kp = 0; kp < 64; ++kp) a = dot2(xs[row][kp], wreg[kp], a);
                out[(size_t)(r0 + row) * 10 + oc + o] = a + obv;
            }
        }
    }
#undef PACKW
#undef MM16
}

extern "C" void kernel_launch(void* const* d_in, const int* in_sizes, int n_in,
                              void* d_out, int out_size, void* d_ws, size_t ws_size,
                              hipStream_t stream)
{
    const float* x   = (const float*)d_in[0];
    const float* Wih = (const float*)d_in[1];
    const float* Whh = (const float*)d_in[2];
    const float* bih = (const float*)d_in[3];
    const float* bhh = (const float*)d_in[4];
    const float* arw = (const float*)d_in[5];
    const float* arb = (const float*)d_in[6];
    const float* aw  = (const float*)d_in[7];
    const float* ab  = (const float*)d_in[8];
    const float* prw = (const float*)d_in[9];
    const float* prb = (const float*)d_in[10];
    const float* pw  = (const float*)d_in[11];
    const float* pb  = (const float*)d_in[12];
    const float* mrw = (const float*)d_in[13];
    const float* mrb = (const float*)d_in[14];
    const float* mw  = (const float*)d_in[15];
    const float* mb  = (const float*)d_in[16];

    const int T = out_size / 10;             // 32768
    u32* enc = (u32*)d_ws;                   // T*64 u32 (f16 pairs) = 8 MB

    rnn_kernel<<<1, 256, 0, stream>>>(x, Wih, Whh, bih, bhh, enc, T);

    heads_kernel<<<dim3(3, (T + 31) / 32), 256, 0, stream>>>(
        enc, arw, arb, aw, ab, prw, prb, pw, pb, mrw, mrb, mw, mb,
        (float*)d_out, T);
}